// Round 7
// baseline (452.060 us; speedup 1.0000x reference)
//
#include <hip/hip_runtime.h>

// ResFCEventuallyLayer — R13: SINGLE fused kernel, no workspace, no convert
// pass. fp32 inputs are staged global->reg->cvt(bf16)->LDS inside the GEMM.
//   rs   = x @ W^T            (einsum "bj,ij->bi": both operands K-major)
//   out1 = relu(1 - beta + rs)
//   res  = relu(1 - (beta_res - (x + out1)));  LeakyReLU(res>=0) == identity
//
// Motivation: total - GEMM has been a CONSTANT 152-156us across all six
// rounds (convert chain ideal ~35us) — the pre-convert + d_ws architecture
// carries ~120us of unexplained cost (convert kernel / workspace re-poison /
// extra launches). This round deletes that phase entirely. GEMM skeleton is
// R10 (best measured: 163us, relaxed 8-phase, one barrier per phase):
//  - LDS layout + inverse-swizzled source mapping UNCHANGED (0 conflicts
//    measured in R3-R6); ds_read side byte-identical.
//  - staging: per 16B chunk, 2x float4 loads + native (__bf16) casts
//    (compiler emits v_cvt_pk_bf16_f32, RNE = same rounding as proven f2bf)
//    + ds_write_b128 to the same linear phys chunk the DMA used.
//  - same phase slots for staging as R9/R10 (WAR table re-verified:
//    A-half h last read P3 -> staged P4/P5; B-half h last read P2 ->
//    staged P3/P4; mirror on odd tiles).
//  - __syncthreads per phase (no async DMA left -> no vmcnt counting;
//    ds_write visibility rides the barrier's lgkm drain).

#define NDIM 4096

typedef __bf16 bf16x8 __attribute__((ext_vector_type(8)));
typedef float f32x4 __attribute__((ext_vector_type(4)));

#define PRIO(x) __builtin_amdgcn_s_setprio(x)

// Stage one half-tile (2 phys rounds): per thread 2x { 2 float4 loads ->
// 8 bf16 casts -> 1 ds_write_b128 }. Dest = linear phys chunk p = rr*512+t
// (byte p*16), same placement the global_load_lds DMA produced before.
#define CHUNK(sbuf, src, offs, bufi, h, S) do { \
    _Pragma("unroll") for (int _c = 0; _c < 2; _c++) { \
        const int _rr = 2 * (h) + _c; \
        const float4* _g = (const float4*)((src) + offs[_rr] + (size_t)(S) * 64); \
        const float4 _a = _g[0], _b = _g[1]; \
        bf16x8 _v; \
        _v[0] = (__bf16)_a.x; _v[1] = (__bf16)_a.y; \
        _v[2] = (__bf16)_a.z; _v[3] = (__bf16)_a.w; \
        _v[4] = (__bf16)_b.x; _v[5] = (__bf16)_b.y; \
        _v[6] = (__bf16)_b.z; _v[7] = (__bf16)_b.w; \
        *(bf16x8*)&sbuf[bufi][_rr * 2048 + tq] = _v; \
    } \
} while (0)

#define CHUNK_A(buf, h, S) CHUNK(sAU, X, offA32, buf, h, S)
#define CHUNK_B(buf, h, S) CHUNK(sBU, W, offB32, buf, h, S)

// ds-read a 4-mt A group (8 x ds_read_b128) / 2-nt B group (4 x b128).
#define READ_A4(dst, pbuf, mt0) do { \
    _Pragma("unroll") for (int _m = 0; _m < 4; _m++) { \
        dst[_m][0] = (pbuf)[afB + ((mt0) + _m) * 128]; \
        dst[_m][1] = (pbuf)[afB + ((mt0) + _m) * 128 + 64]; } \
} while (0)
#define READ_B2(dst, pbuf, nt0) do { \
    _Pragma("unroll") for (int _n = 0; _n < 2; _n++) { \
        dst[_n][0] = (pbuf)[bfB + ((nt0) + _n) * 128]; \
        dst[_n][1] = (pbuf)[bfB + ((nt0) + _n) * 128 + 64]; } \
} while (0)

// One C-quadrant x K=64: ksub outer -> 8 independent MFMAs per pass.
#define MM16(afr, bfr, mt0, nt0) do { \
    _Pragma("unroll") for (int _k = 0; _k < 2; _k++) \
    _Pragma("unroll") for (int _m = 0; _m < 4; _m++) \
    _Pragma("unroll") for (int _n = 0; _n < 2; _n++) \
        acc[(mt0)+_m][(nt0)+_n] = __builtin_amdgcn_mfma_f32_16x16x32_bf16( \
            afr[_m][_k], bfr[_n][_k], acc[(mt0)+_m][(nt0)+_n], 0, 0, 0); \
} while (0)

// 256x256 tile, BK=64, 8 waves (2Mx4N), dbuf, in-register fp32->bf16 staging.
__global__ void __launch_bounds__(512, 2)
ResFCEventuallyLayer_82205674045459_kernel(
    const float* X, const float* W,
    const float* Bp, const float* Br,
    float* out)
{
    // Per buffer: 256 rows x 64 k x bf16 = 32KB = 32 subtiles x 1KB.
    // Subtile (sr = row>>4, sc = kcol>>5) at byte (sr*2+sc)*1024; within:
    // r = row&15, phys chunk-in-row = logical chunk ^ ((r>>3)<<1).
    __shared__ __align__(16) unsigned int sAU[2][8192];
    __shared__ __align__(16) unsigned int sBU[2][8192];

    const int t    = threadIdx.x;      // 0..511
    const int lane = t & 63;
    const int wave = t >> 6;           // 0..7
    const int quad = lane >> 4;        // 0..3
    const int l16  = lane & 15;
    const int wm   = wave >> 2;        // 0..1: 128-row half
    const int wn   = wave & 3;         // 0..3: 64-col quarter
    const int tq   = t * 4;            // uint index of thread's 16B chunk slot

    // 256 blocks total (= 1/CU); bijective XCD swizzle (256 % 8 == 0).
    const int bid = blockIdx.x;
    const int swz = ((bid & 7) << 5) | (bid >> 3);
    const int bm0 = (swz >> 4) * 256;
    const int bn0 = (swz & 15) * 256;

    // Inverse-swizzle the fp32 source for the linear LDS dest (rule 21):
    // phys chunk p = rr*512 + t -> row, logical k-chunk gc; float offset =
    // (tile_row)*4096 + gc*8 (+ S*64 per K-tile).
    size_t offA32[4], offB32[4];
#pragma unroll
    for (int rr = 0; rr < 4; rr++) {
        const int p   = rr * 512 + t;
        const int r   = (p >> 2) & 15;
        const int sub = p >> 6;               // 0..31
        const int sr  = sub >> 1, sc = sub & 1;
        const int c8  = (p & 3) ^ (((r >> 3) & 1) << 1);
        const int row = sr * 16 + r;
        const int gc  = sc * 4 + c8;          // logical 8-elem chunk in K-tile
        offA32[rr] = (size_t)(bm0 + row) * NDIM + gc * 8;
        offB32[rr] = (size_t)(bn0 + row) * NDIM + gc * 8;
    }

    // Fragment ds_read addressing (matches staged swizzle); conflict-free:
    // byte = subtile*1024 + l16*64 + (quad*16 ^ ((l16>>3)<<5)).
    const int laneByte = l16 * 64 + ((quad * 16) ^ (((l16 >> 3) & 1) << 5));
    const int afB = (wm * 16384 + laneByte) >> 4;   // bf16x8 units
    const int bfB = (wn * 8192  + laneByte) >> 4;

    const bf16x8* pA0 = (const bf16x8*)sAU[0];
    const bf16x8* pA1 = (const bf16x8*)sAU[1];
    const bf16x8* pB0 = (const bf16x8*)sBU[0];
    const bf16x8* pB1 = (const bf16x8*)sBU[1];

    f32x4 acc[8][4];
#pragma unroll
    for (int i = 0; i < 8; i++)
#pragma unroll
        for (int j = 0; j < 4; j++)
#pragma unroll
            for (int r = 0; r < 4; r++)
                acc[i][j][r] = 0.0f;

    bf16x8 af0[4][2], af1[4][2], bf0[2][2], bf1[2][2];

    // Prologue: stage tile0 -> buf0 and tile1 -> buf1 (reg-staged).
    CHUNK_A(0, 0, 0); CHUNK_A(0, 1, 0); CHUNK_B(0, 0, 0); CHUNK_B(0, 1, 0);
    CHUNK_A(1, 0, 1); CHUNK_A(1, 1, 1); CHUNK_B(1, 0, 1); CHUNK_B(1, 1, 1);
    __syncthreads();

    // 64 K-tiles, 2 per iteration (buf0 = even tile, buf1 = odd tile).
    // Stage slots identical to R9/R10 (WAR/RAW table in header).
    for (int j = 0; j < 32; j++) {
        const int S1 = 2 * j + 1;              // <= 63, no clamp
        const int S2 = (2 * j + 2) & 63;       // garbage-safe wrap on last iter
        const int S3 = (2 * j + 3) & 63;

        // ---- even tile 2j (buf0): quadrants Q00,Q01,Q11,Q10 ----
        // P1: stage buf1.A1 (last read prev P7)
        CHUNK_A(1, 1, S1);
        READ_A4(af0, pA0, 0); READ_B2(bf0, pB0, 0);
        PRIO(1); MM16(af0, bf0, 0, 0); PRIO(0);          // Q00
        __syncthreads();
        // P2: no stage (all buf0 halves still have pending reads)
        READ_B2(bf1, pB0, 2);
        PRIO(1); MM16(af0, bf1, 0, 2); PRIO(0);          // Q01
        __syncthreads();
        // P3: stage buf0.B0 for tile 2j+2 (B last read P2)
        CHUNK_B(0, 0, S2);
        READ_A4(af1, pA0, 4);
        PRIO(1); MM16(af1, bf1, 4, 2); PRIO(0);          // Q11
        __syncthreads();
        // P4: stage buf0.B1 + buf0.A0 (A last read P3)
        CHUNK_B(0, 1, S2);
        CHUNK_A(0, 0, S2);
        PRIO(1); MM16(af1, bf0, 4, 0); PRIO(0);          // Q10
        __syncthreads();

        // ---- odd tile 2j+1 (buf1) ----
        // P5: stage buf0.A1 (last read P3)
        CHUNK_A(0, 1, S2);
        READ_A4(af0, pA1, 0); READ_B2(bf0, pB1, 0);
        PRIO(1); MM16(af0, bf0, 0, 0); PRIO(0);
        __syncthreads();
        // P6
        READ_B2(bf1, pB1, 2);
        PRIO(1); MM16(af0, bf1, 0, 2); PRIO(0);
        __syncthreads();
        // P7: stage buf1.B0 for tile 2j+3 (last read P6)
        CHUNK_B(1, 0, S3);
        READ_A4(af1, pA1, 4);
        PRIO(1); MM16(af1, bf1, 4, 2); PRIO(0);
        __syncthreads();
        // P8: stage buf1.B1 + buf1.A0 (last read P7)
        CHUNK_B(1, 1, S3);
        CHUNK_A(1, 0, S3);
        PRIO(1); MM16(af1, bf0, 4, 0); PRIO(0);
        __syncthreads();
    }

    // Fused epilogue. C/D layout: n(col) = lane&15, m(row) = quad*4 + reg.
    const float one_m_beta = 1.0f - Bp[0];
#pragma unroll
    for (int nt = 0; nt < 4; nt++) {
        const int n = bn0 + wn * 64 + nt * 16 + l16;
        const float br = Br[n];
#pragma unroll
        for (int mt = 0; mt < 8; mt++) {
            const int mbase = bm0 + wm * 128 + mt * 16 + quad * 4;
#pragma unroll
            for (int r = 0; r < 4; r++) {
                const size_t idx = (size_t)(mbase + r) * NDIM + n;
                float v = acc[mt][nt][r] + one_m_beta;
                if (v < 0.0f) v = 0.0f;                 // relu(1 - beta + rowsum)
                float res = 1.0f - br + X[idx] + v;
                if (res < 0.0f) res = 0.0f;             // relu; leaky on relu == id
                out[idx] = res;
            }
        }
    }
}

extern "C" void kernel_launch(void* const* d_in, const int* in_sizes, int n_in,
                              void* d_out, int out_size, void* d_ws, size_t ws_size,
                              hipStream_t stream) {
    (void)in_sizes; (void)n_in; (void)out_size; (void)d_ws; (void)ws_size;

    const float* X  = (const float*)d_in[0];
    const float* W  = (const float*)d_in[1];
    const float* Bp = (const float*)d_in[2];
    const float* Br = (const float*)d_in[3];
    float* out      = (float*)d_out;

    hipLaunchKernelGGL(ResFCEventuallyLayer_82205674045459_kernel,
                       dim3(256), dim3(512), 0, stream, X, W, Bp, Br, out);
}

// Round 8
// 327.539 us; speedup vs baseline: 1.3802x; 1.3802x over previous
//
#include <hip/hip_runtime.h>

// ResFCEventuallyLayer — (1) fused fp32->bf16 pre-convert into d_ws,
// (2) 256x256 8-phase bf16 MFMA GEMM (counted vmcnt) + fused epilogue.
//   rs   = x @ W^T            (einsum "bj,ij->bi": both operands K-major)
//   out1 = relu(1 - beta + rs)
//   res  = relu(1 - (beta_res - (x + out1)));  LeakyReLU(res>=0) == identity
//
// R14 (vs R10, best measured 163us GEMM): uniform stage distribution at
// 64-row-ROUND granularity. Cost ledger (R13 experiment): total = ~100us
// fixed harness + ~55us convert (near its 192MB roofline) + GEMM.
// WAR table (rounds = 64 rows = 1 gload/thread), per tile in buf0:
//   A rounds {0,2} read entirely at P1 (af0); {1,3} at P3 (af1);
//   B rounds {0..3} read across P1+P2 (bf0,bf1) -> free after P2.
// Stage slots (2 gloads/phase; P6:0, P7:4):
//   P1: buf1.A{1,3}@S1 | P2: buf0.A{0,2}@S2 | P3: buf0.B{0,1}@S2
//   P4: buf0.B{2,3}@S2 | P5: buf0.A{1,3}@S2 | P7: buf1.B{0..3}@S3
//   P8: buf1.A{0,2}@S3
// RAW gates: VMCNT(6) at P4 (drains buf1's rounds: prevP7 x4, prevP8 x2,
// P1 x2; outstanding after = P2+P3+P4 = 6) and P8 (drains buf0's rounds
// P2..P5; outstanding after = P7 x4 + P8 x2 = 6). Raw s_barrier per phase;
// no lgkm drains (compiler's fine-grained lgkmcnt covers ds_read->MFMA).

#define NDIM 4096

typedef __bf16 bf16x8 __attribute__((ext_vector_type(8)));
typedef float f32x4 __attribute__((ext_vector_type(4)));

__device__ unsigned short f2bf(float f) {
    unsigned int x;
    __builtin_memcpy(&x, &f, 4);
    unsigned int r = x + 0x7FFFu + ((x >> 16) & 1u);   // round-to-nearest-even
    return (unsigned short)(r >> 16);
}

__device__ unsigned int pack_bf2(float lo, float hi) {
    return (unsigned int)f2bf(lo) | ((unsigned int)f2bf(hi) << 16);
}

// Direct global->LDS DMA, 16 B per lane: wave-uniform LDS base + lane*16.
__device__ inline void gload16(const uint4* g, unsigned int* l) {
    __builtin_amdgcn_global_load_lds(
        (const __attribute__((address_space(1))) unsigned int*)g,
        (__attribute__((address_space(3))) unsigned int*)l,
        16, 0, 0);
}

// Phase 1 (fused): fp32 -> packed bf16 for BOTH X and W in one launch.
__global__ void convert_f32_bf16_kernel(const float* X, unsigned int* Xbf,
                                        const float* W, unsigned int* Wbf) {
    unsigned int bid = blockIdx.x;
    const float* src;
    unsigned int* dst;
    if (bid < 8192) { src = X; dst = Xbf; }
    else            { src = W; dst = Wbf; bid -= 8192; }
    const size_t i = ((size_t)bid * blockDim.x + threadIdx.x) * 8;
    float4 v0 = *(const float4*)(src + i);
    float4 v1 = *(const float4*)(src + i + 4);
    uint4 u;
    u.x = pack_bf2(v0.x, v0.y);
    u.y = pack_bf2(v0.z, v0.w);
    u.z = pack_bf2(v1.x, v1.y);
    u.w = pack_bf2(v1.z, v1.w);
    *(uint4*)(dst + i / 2) = u;
}

#define BAR()   __builtin_amdgcn_s_barrier()
#define VMCNT(n) asm volatile("s_waitcnt vmcnt(" #n ")" ::: "memory")
#define PRIO(x) __builtin_amdgcn_s_setprio(x)

// Stage one 64-row round (1 gload16 per thread = 8KB).
#define STAGE1_A(buf, rr, S) \
    gload16(Ab4 + (offA[rr] + (S) * 8), &sAU[buf][(rr) * 2048 + wq])
#define STAGE1_B(buf, rr, S) \
    gload16(Bb4 + (offB[rr] + (S) * 8), &sBU[buf][(rr) * 2048 + wq])

// ds-read a 4-mt A group (8 x ds_read_b128) / 2-nt B group (4 x b128).
#define READ_A4(dst, pbuf, mt0) do { \
    _Pragma("unroll") for (int _m = 0; _m < 4; _m++) { \
        dst[_m][0] = (pbuf)[afB + ((mt0) + _m) * 128]; \
        dst[_m][1] = (pbuf)[afB + ((mt0) + _m) * 128 + 64]; } \
} while (0)
#define READ_B2(dst, pbuf, nt0) do { \
    _Pragma("unroll") for (int _n = 0; _n < 2; _n++) { \
        dst[_n][0] = (pbuf)[bfB + ((nt0) + _n) * 128]; \
        dst[_n][1] = (pbuf)[bfB + ((nt0) + _n) * 128 + 64]; } \
} while (0)

// One C-quadrant x K=64: ksub outer -> 8 independent MFMAs per pass.
#define MM16(afr, bfr, mt0, nt0) do { \
    _Pragma("unroll") for (int _k = 0; _k < 2; _k++) \
    _Pragma("unroll") for (int _m = 0; _m < 4; _m++) \
    _Pragma("unroll") for (int _n = 0; _n < 2; _n++) \
        acc[(mt0)+_m][(nt0)+_n] = __builtin_amdgcn_mfma_f32_16x16x32_bf16( \
            afr[_m][_k], bfr[_n][_k], acc[(mt0)+_m][(nt0)+_n], 0, 0, 0); \
} while (0)

// Phase 2: 256x256 tile, BK=64, 8 waves (2Mx4N), 8-phase counted-vmcnt loop.
__global__ void __launch_bounds__(512, 2)
ResFCEventuallyLayer_82205674045459_kernel(
    const unsigned int* Xbf, const unsigned int* Wbf,
    const float* X, const float* Bp, const float* Br,
    float* out)
{
    // Per buffer: 256 rows x 64 k x bf16 = 32KB = 32 subtiles x 1KB.
    // Subtile (sr = row>>4, sc = kcol>>5) at byte (sr*2+sc)*1024; within:
    // r = row&15, phys chunk-in-row = logical chunk ^ ((r>>3)<<1).
    __shared__ __align__(16) unsigned int sAU[2][8192];
    __shared__ __align__(16) unsigned int sBU[2][8192];

    const int t    = threadIdx.x;      // 0..511
    const int lane = t & 63;
    const int wave = t >> 6;           // 0..7
    const int quad = lane >> 4;        // 0..3
    const int l16  = lane & 15;
    const int wm   = wave >> 2;        // 0..1: 128-row half
    const int wn   = wave & 3;         // 0..3: 64-col quarter
    const int wq   = wave * 256;       // LDS uint offset of wave's 1KB DMA slice

    // 256 blocks total (= 1/CU); bijective XCD swizzle (256 % 8 == 0).
    const int bid = blockIdx.x;
    const int swz = ((bid & 7) << 5) | (bid >> 3);
    const int bm0 = (swz >> 4) * 256;
    const int bn0 = (swz & 15) * 256;

    const uint4* Ab4 = (const uint4*)Xbf;   // 512 uint4 per global row
    const uint4* Bb4 = (const uint4*)Wbf;

    // Staging inverse-swizzle: round rr writes phys chunks p = rr*512 + t
    // (lane*16B within wave slice). Invert phys->logical for the global src.
    int offA[4], offB[4];
#pragma unroll
    for (int rr = 0; rr < 4; rr++) {
        const int p   = rr * 512 + t;
        const int r   = (p >> 2) & 15;
        const int sub = p >> 6;               // 0..31
        const int sr  = sub >> 1, sc = sub & 1;
        const int c8  = (p & 3) ^ (((r >> 3) & 1) << 1);
        const int row = sr * 16 + r;
        const int gc  = sc * 4 + c8;          // logical 8-col chunk in K-tile
        offA[rr] = (bm0 + row) * 512 + gc;
        offB[rr] = (bn0 + row) * 512 + gc;
    }

    // Fragment ds_read addressing (matches the staged swizzle):
    // byte = subtile*1024 + l16*64 + (quad*16 ^ ((l16>>3)<<5)); conflict-free.
    const int laneByte = l16 * 64 + ((quad * 16) ^ (((l16 >> 3) & 1) << 5));
    const int afB = (wm * 16384 + laneByte) >> 4;   // bf16x8 units
    const int bfB = (wn * 8192  + laneByte) >> 4;

    const bf16x8* pA0 = (const bf16x8*)sAU[0];
    const bf16x8* pA1 = (const bf16x8*)sAU[1];
    const bf16x8* pB0 = (const bf16x8*)sBU[0];
    const bf16x8* pB1 = (const bf16x8*)sBU[1];

    f32x4 acc[8][4];
#pragma unroll
    for (int i = 0; i < 8; i++)
#pragma unroll
        for (int j = 0; j < 4; j++)
#pragma unroll
            for (int r = 0; r < 4; r++)
                acc[i][j][r] = 0.0f;

    bf16x8 af0[4][2], af1[4][2], bf0[2][2], bf1[2][2];

    // Prologue: tile0 -> buf0 (8 rounds) + tile1 -> buf1 rounds matching the
    // P7/P8 slots (B0-3, A0, A2). Loop-P1 completes tile1 (A1, A3).
    STAGE1_A(0, 0, 0); STAGE1_A(0, 1, 0); STAGE1_A(0, 2, 0); STAGE1_A(0, 3, 0);
    STAGE1_B(0, 0, 0); STAGE1_B(0, 1, 0); STAGE1_B(0, 2, 0); STAGE1_B(0, 3, 0);
    STAGE1_B(1, 0, 1); STAGE1_B(1, 1, 1); STAGE1_B(1, 2, 1); STAGE1_B(1, 3, 1);
    STAGE1_A(1, 0, 1); STAGE1_A(1, 2, 1);
    VMCNT(6);          // tile0's 8 landed; tile1's 6 in flight
    BAR();

    // 64 K-tiles, 2 per iteration (buf0 = even tile, buf1 = odd tile).
    // One raw barrier per phase; stages at phase top (2 gloads, P7: 4).
    for (int j = 0; j < 32; j++) {
        const int S1 = 2 * j + 1;              // <= 63, no clamp
        const int S2 = (2 * j + 2) & 63;       // garbage-safe wrap on last iter
        const int S3 = (2 * j + 3) & 63;

        // ---- even tile 2j (buf0): Q00,Q01,Q11,Q10 ----
        // P1: finish buf1 A{1,3} (last read prev P7)
        STAGE1_A(1, 1, S1); STAGE1_A(1, 3, S1);
        READ_A4(af0, pA0, 0); READ_B2(bf0, pB0, 0);
        PRIO(1); MM16(af0, bf0, 0, 0); PRIO(0);          // Q00
        BAR();
        // P2: buf0 A{0,2} (rows fully read at P1 into af0)
        STAGE1_A(0, 0, S2); STAGE1_A(0, 2, S2);
        READ_B2(bf1, pB0, 2);
        PRIO(1); MM16(af0, bf1, 0, 2); PRIO(0);          // Q01
        BAR();
        // P3: buf0 B{0,1} (B fully read by P2)
        STAGE1_B(0, 0, S2); STAGE1_B(0, 1, S2);
        READ_A4(af1, pA0, 4);
        PRIO(1); MM16(af1, bf1, 4, 2); PRIO(0);          // Q11
        BAR();
        // P4: buf0 B{2,3}; gate buf1 (outstanding after = P2+P3+P4 = 6)
        STAGE1_B(0, 2, S2); STAGE1_B(0, 3, S2);
        PRIO(1); MM16(af1, bf0, 4, 0); PRIO(0);          // Q10
        VMCNT(6);
        BAR();

        // ---- odd tile 2j+1 (buf1): Q00,Q01,Q11,Q10 ----
        // P5: buf0 A{1,3} (last read P3 into af1)
        STAGE1_A(0, 1, S2); STAGE1_A(0, 3, S2);
        READ_A4(af0, pA1, 0); READ_B2(bf0, pB1, 0);
        PRIO(1); MM16(af0, bf0, 0, 0); PRIO(0);
        BAR();
        // P6: no stage (buf1 B still being read this phase)
        READ_B2(bf1, pB1, 2);
        PRIO(1); MM16(af0, bf1, 0, 2); PRIO(0);
        BAR();
        // P7: buf1 B{0..3} (B fully read by P6)
        STAGE1_B(1, 0, S3); STAGE1_B(1, 1, S3);
        STAGE1_B(1, 2, S3); STAGE1_B(1, 3, S3);
        READ_A4(af1, pA1, 4);
        PRIO(1); MM16(af1, bf1, 4, 2); PRIO(0);
        BAR();
        // P8: buf1 A{0,2} (last read P5); gate buf0 (after = P7x4 + P8x2 = 6)
        STAGE1_A(1, 0, S3); STAGE1_A(1, 2, S3);
        PRIO(1); MM16(af1, bf0, 4, 0); PRIO(0);
        VMCNT(6);
        BAR();
    }

    // Fused epilogue. C/D layout: n(col) = lane&15, m(row) = quad*4 + reg.
    const float one_m_beta = 1.0f - Bp[0];
#pragma unroll
    for (int nt = 0; nt < 4; nt++) {
        const int n = bn0 + wn * 64 + nt * 16 + l16;
        const float br = Br[n];
#pragma unroll
        for (int mt = 0; mt < 8; mt++) {
            const int mbase = bm0 + wm * 128 + mt * 16 + quad * 4;
#pragma unroll
            for (int r = 0; r < 4; r++) {
                const size_t idx = (size_t)(mbase + r) * NDIM + n;
                float v = acc[mt][nt][r] + one_m_beta;
                if (v < 0.0f) v = 0.0f;                 // relu(1 - beta + rowsum)
                float res = 1.0f - br + X[idx] + v;
                if (res < 0.0f) res = 0.0f;             // relu; leaky on relu == id
                out[idx] = res;
            }
        }
    }
}

// Fallback (R6 kernel, proven): in-loop conversion, no workspace needed.
__global__ void resfc_fallback_kernel(
    const float* X, const float* W,
    const float* Bp, const float* Br,
    float* out)
{
    __shared__ __align__(16) unsigned int sA[128 * 16];
    __shared__ __align__(16) unsigned int sB[128 * 16];

    const int t    = threadIdx.x;
    const int lane = t & 63;
    const int wave = t >> 6;
    const int quad = lane >> 4;
    const int l16  = lane & 15;
    const int wm   = wave >> 1;
    const int wn   = wave & 1;

    const int bm0 = blockIdx.y * 128;
    const int bn0 = blockIdx.x * 128;

    const float* gA[4];
    const float* gB[4];
    int ldsIdx[4];
    for (int c = 0; c < 4; c++) {
        const int ch   = t + c * 256;
        const int row  = ch >> 3;
        const int col4 = ch & 7;
        gA[c] = X + (size_t)(bm0 + row) * NDIM + col4 * 4;
        gB[c] = W + (size_t)(bn0 + row) * NDIM + col4 * 4;
        ldsIdx[c] = row * 16 + col4 * 2;
    }

    const bf16x8* pa = (const bf16x8*)sA + (wm * 64 + l16) * 4 + quad;
    const bf16x8* pb = (const bf16x8*)sB + (wn * 64 + l16) * 4 + quad;

    f32x4 acc[4][4];
    for (int i = 0; i < 4; i++)
        for (int j = 0; j < 4; j++)
            for (int r = 0; r < 4; r++)
                acc[i][j][r] = 0.0f;

    for (int k0 = 0; k0 < NDIM; k0 += 32) {
        float4 va[4], vb[4];
        for (int c = 0; c < 4; c++) {
            va[c] = *(const float4*)(gA[c] + k0);
            vb[c] = *(const float4*)(gB[c] + k0);
        }
        __syncthreads();
        for (int c = 0; c < 4; c++) {
            uint2 ua, ub;
            ua.x = pack_bf2(va[c].x, va[c].y);
            ua.y = pack_bf2(va[c].z, va[c].w);
            ub.x = pack_bf2(vb[c].x, vb[c].y);
            ub.y = pack_bf2(vb[c].z, vb[c].w);
            *(uint2*)(sA + ldsIdx[c]) = ua;
            *(uint2*)(sB + ldsIdx[c]) = ub;
        }
        __syncthreads();

        bf16x8 af[4], bfr[4];
        for (int mt = 0; mt < 4; mt++) af[mt]  = pa[mt * 64];
        for (int nt = 0; nt < 4; nt++) bfr[nt] = pb[nt * 64];

        for (int mt = 0; mt < 4; mt++)
            for (int nt = 0; nt < 4; nt++)
                acc[mt][nt] = __builtin_amdgcn_mfma_f32_16x16x32_bf16(
                    af[mt], bfr[nt], acc[mt][nt], 0, 0, 0);
    }

    const float one_m_beta = 1.0f - Bp[0];
    for (int nt = 0; nt < 4; nt++) {
        const int n = bn0 + wn * 64 + nt * 16 + l16;
        const float br = Br[n];
        for (int mt = 0; mt < 4; mt++) {
            const int mbase = bm0 + wm * 64 + mt * 16 + quad * 4;
            for (int r = 0; r < 4; r++) {
                const size_t idx = (size_t)(mbase + r) * NDIM + n;
                float v = acc[mt][nt][r] + one_m_beta;
                if (v < 0.0f) v = 0.0f;
                float res = 1.0f - br + X[idx] + v;
                if (res < 0.0f) res = 0.0f;
                out[idx] = res;
            }
        }
    }
}

extern "C" void kernel_launch(void* const* d_in, const int* in_sizes, int n_in,
                              void* d_out, int out_size, void* d_ws, size_t ws_size,
                              hipStream_t stream) {
    (void)in_sizes; (void)n_in; (void)out_size;

    const float* X  = (const float*)d_in[0];
    const float* W  = (const float*)d_in[1];
    const float* Bp = (const float*)d_in[2];
    const float* Br = (const float*)d_in[3];
    float* out      = (float*)d_out;

    const size_t elems   = (size_t)NDIM * NDIM;          // 16.7M per matrix
    const size_t bf_need = elems * 2 * 2;                // Xbf + Wbf, 2 B each

    if (ws_size >= bf_need) {
        unsigned int* Xbf = (unsigned int*)d_ws;
        unsigned int* Wbf = (unsigned int*)d_ws + elems / 2;   // uint = 2 bf16

        hipLaunchKernelGGL(convert_f32_bf16_kernel, dim3(16384), dim3(256),
                           0, stream, X, Xbf, W, Wbf);
        hipLaunchKernelGGL(ResFCEventuallyLayer_82205674045459_kernel,
                           dim3(256), dim3(512), 0, stream, Xbf, Wbf, X, Bp, Br, out);
    } else {
        hipLaunchKernelGGL(resfc_fallback_kernel,
                           dim3(NDIM / 128, NDIM / 128), dim3(256), 0, stream,
                           X, W, Bp, Br, out);
    }
}

// Round 9
// 294.747 us; speedup vs baseline: 1.5337x; 1.1113x over previous
//
#include <hip/hip_runtime.h>

// ResFCEventuallyLayer — (1) fused fp32->bf16 pre-convert into d_ws,
// (2) 256x256 6-phase bf16 MFMA GEMM (counted vmcnt) + fused epilogue.
//   rs   = x @ W^T            (einsum "bj,ij->bi": both operands K-major)
//   out1 = relu(1 - beta + rs)
//   res  = relu(1 - (beta_res - (x + out1)));  LeakyReLU(res>=0) == identity
//
// R15 (vs R10 = best measured 163us GEMM of 6 schedule variants):
//  1. Remove the two provably-dead barriers (P1->P2, P5->P6): those stages
//     touch the OTHER buffer and P2/P6 stage nothing -> no WAR/RAW crosses
//     them. Merged super-phases {stage 2, 16 ds_read, Q00+Q01 (32 MFMA)}.
//     Re-audited ledger (STAGE_X = 2 gloads):
//       P4 gate: 6 + P12:2 + P3:2 + P4:4 = 14 -> drain 8 = buf1's
//       {prevP7 B0, prevP8 B1+A0, P12 A1} before P56 reads buf1.
//       P8 gate: 6 + P56:2 + P7:2 + P8:4 = 14 -> drain 8 = buf0's
//       {P3 B0, P4 B1+A0, P56 A1} before next P12 reads buf0.
//     WAR: every stage has >=1 end-of-phase barrier after its region's
//     chip-wide last read (stage targets listed per phase below).
//  2. Epilogue reads X via its bf16 copy Xbf (L2-warm: same rows this block
//     just streamed as A-tiles) -> X traffic halved; error ~2^-8 abs on a
//     2.0-vs-7.32 margin. out stored non-temporally (never re-read).

#define NDIM 4096

typedef __bf16 bf16x8 __attribute__((ext_vector_type(8)));
typedef float f32x4 __attribute__((ext_vector_type(4)));

__device__ unsigned short f2bf(float f) {
    unsigned int x;
    __builtin_memcpy(&x, &f, 4);
    unsigned int r = x + 0x7FFFu + ((x >> 16) & 1u);   // round-to-nearest-even
    return (unsigned short)(r >> 16);
}

__device__ unsigned int pack_bf2(float lo, float hi) {
    return (unsigned int)f2bf(lo) | ((unsigned int)f2bf(hi) << 16);
}

// Direct global->LDS DMA, 16 B per lane: wave-uniform LDS base + lane*16.
__device__ inline void gload16(const uint4* g, unsigned int* l) {
    __builtin_amdgcn_global_load_lds(
        (const __attribute__((address_space(1))) unsigned int*)g,
        (__attribute__((address_space(3))) unsigned int*)l,
        16, 0, 0);
}

// Phase 1 (fused): fp32 -> packed bf16 for BOTH X and W in one launch.
__global__ void convert_f32_bf16_kernel(const float* X, unsigned int* Xbf,
                                        const float* W, unsigned int* Wbf) {
    unsigned int bid = blockIdx.x;
    const float* src;
    unsigned int* dst;
    if (bid < 8192) { src = X; dst = Xbf; }
    else            { src = W; dst = Wbf; bid -= 8192; }
    const size_t i = ((size_t)bid * blockDim.x + threadIdx.x) * 8;
    float4 v0 = *(const float4*)(src + i);
    float4 v1 = *(const float4*)(src + i + 4);
    uint4 u;
    u.x = pack_bf2(v0.x, v0.y);
    u.y = pack_bf2(v0.z, v0.w);
    u.z = pack_bf2(v1.x, v1.y);
    u.w = pack_bf2(v1.z, v1.w);
    *(uint4*)(dst + i / 2) = u;
}

#define BAR()   __builtin_amdgcn_s_barrier()
#define VMCNT(n) asm volatile("s_waitcnt vmcnt(" #n ")" ::: "memory")
#define PRIO(x) __builtin_amdgcn_s_setprio(x)

// Stage one half-tile (2 rounds x 8KB). buf/h are literals.
#define STAGE_A(buf, h, S) do { \
    gload16(Ab4 + (offA[2*(h)]   + (S)*8), &sAU[buf][(2*(h))*2048   + wq]); \
    gload16(Ab4 + (offA[2*(h)+1] + (S)*8), &sAU[buf][(2*(h)+1)*2048 + wq]); \
} while (0)
#define STAGE_B(buf, h, S) do { \
    gload16(Bb4 + (offB[2*(h)]   + (S)*8), &sBU[buf][(2*(h))*2048   + wq]); \
    gload16(Bb4 + (offB[2*(h)+1] + (S)*8), &sBU[buf][(2*(h)+1)*2048 + wq]); \
} while (0)

// ds-read a 4-mt A group (8 x ds_read_b128) / 2-nt B group (4 x b128).
#define READ_A4(dst, pbuf, mt0) do { \
    _Pragma("unroll") for (int _m = 0; _m < 4; _m++) { \
        dst[_m][0] = (pbuf)[afB + ((mt0) + _m) * 128]; \
        dst[_m][1] = (pbuf)[afB + ((mt0) + _m) * 128 + 64]; } \
} while (0)
#define READ_B2(dst, pbuf, nt0) do { \
    _Pragma("unroll") for (int _n = 0; _n < 2; _n++) { \
        dst[_n][0] = (pbuf)[bfB + ((nt0) + _n) * 128]; \
        dst[_n][1] = (pbuf)[bfB + ((nt0) + _n) * 128 + 64]; } \
} while (0)

// One C-quadrant x K=64: ksub outer -> 8 independent MFMAs per pass.
#define MM16(afr, bfr, mt0, nt0) do { \
    _Pragma("unroll") for (int _k = 0; _k < 2; _k++) \
    _Pragma("unroll") for (int _m = 0; _m < 4; _m++) \
    _Pragma("unroll") for (int _n = 0; _n < 2; _n++) \
        acc[(mt0)+_m][(nt0)+_n] = __builtin_amdgcn_mfma_f32_16x16x32_bf16( \
            afr[_m][_k], bfr[_n][_k], acc[(mt0)+_m][(nt0)+_n], 0, 0, 0); \
} while (0)

// Phase 2: 256x256 tile, BK=64, 8 waves (2Mx4N), 6-phase counted-vmcnt loop.
__global__ void __launch_bounds__(512, 2)
ResFCEventuallyLayer_82205674045459_kernel(
    const unsigned int* Xbf, const unsigned int* Wbf,
    const float* X, const float* Bp, const float* Br,
    float* out)
{
    // Per buffer: 256 rows x 64 k x bf16 = 32KB = 32 subtiles x 1KB.
    // Subtile (sr = row>>4, sc = kcol>>5) at byte (sr*2+sc)*1024; within:
    // r = row&15, phys chunk-in-row = logical chunk ^ ((r>>3)<<1).
    __shared__ __align__(16) unsigned int sAU[2][8192];
    __shared__ __align__(16) unsigned int sBU[2][8192];

    const int t    = threadIdx.x;      // 0..511
    const int lane = t & 63;
    const int wave = t >> 6;           // 0..7
    const int quad = lane >> 4;        // 0..3
    const int l16  = lane & 15;
    const int wm   = wave >> 2;        // 0..1: 128-row half
    const int wn   = wave & 3;         // 0..3: 64-col quarter
    const int wq   = wave * 256;       // LDS uint offset of wave's 1KB DMA slice

    // 256 blocks total (= 1/CU); bijective XCD swizzle (256 % 8 == 0).
    const int bid = blockIdx.x;
    const int swz = ((bid & 7) << 5) | (bid >> 3);
    const int bm0 = (swz >> 4) * 256;
    const int bn0 = (swz & 15) * 256;

    const uint4* Ab4 = (const uint4*)Xbf;   // 512 uint4 per global row
    const uint4* Bb4 = (const uint4*)Wbf;

    // Staging inverse-swizzle: round rr writes phys chunks p = rr*512 + t
    // (lane*16B within wave slice). Invert phys->logical for the global src.
    int offA[4], offB[4];
#pragma unroll
    for (int rr = 0; rr < 4; rr++) {
        const int p   = rr * 512 + t;
        const int r   = (p >> 2) & 15;
        const int sub = p >> 6;               // 0..31
        const int sr  = sub >> 1, sc = sub & 1;
        const int c8  = (p & 3) ^ (((r >> 3) & 1) << 1);
        const int row = sr * 16 + r;
        const int gc  = sc * 4 + c8;          // logical 8-col chunk in K-tile
        offA[rr] = (bm0 + row) * 512 + gc;
        offB[rr] = (bn0 + row) * 512 + gc;
    }

    // Fragment ds_read addressing (matches the staged swizzle):
    // byte = subtile*1024 + l16*64 + (quad*16 ^ ((l16>>3)<<5)); conflict-free.
    const int laneByte = l16 * 64 + ((quad * 16) ^ (((l16 >> 3) & 1) << 5));
    const int afB = (wm * 16384 + laneByte) >> 4;   // bf16x8 units
    const int bfB = (wn * 8192  + laneByte) >> 4;

    const bf16x8* pA0 = (const bf16x8*)sAU[0];
    const bf16x8* pA1 = (const bf16x8*)sAU[1];
    const bf16x8* pB0 = (const bf16x8*)sBU[0];
    const bf16x8* pB1 = (const bf16x8*)sBU[1];

    f32x4 acc[8][4];
#pragma unroll
    for (int i = 0; i < 8; i++)
#pragma unroll
        for (int j = 0; j < 4; j++)
#pragma unroll
            for (int r = 0; r < 4; r++)
                acc[i][j][r] = 0.0f;

    bf16x8 af0[4][2], af1[4][2], bf0[2][2], bf1[2][2];

    // Prologue: tile0 (A0,B0,B1,A1) + tile1 (A0,B0,B1) = 7 halves, 14 loads.
    STAGE_A(0, 0, 0); STAGE_B(0, 0, 0); STAGE_B(0, 1, 0); STAGE_A(0, 1, 0);
    STAGE_A(1, 0, 1); STAGE_B(1, 0, 1); STAGE_B(1, 1, 1);
    VMCNT(6);          // tile0's 8 loads landed; tile1's 6 in flight
    BAR();

    // 64 K-tiles, 2 per iteration (buf0 = even tile, buf1 = odd tile).
    for (int j = 0; j < 32; j++) {
        const int S1 = 2 * j + 1;              // <= 63, no clamp
        const int S2 = (2 * j + 2) & 63;       // garbage-safe wrap on last iter
        const int S3 = (2 * j + 3) & 63;

        // ---- even tile 2j (buf0) ----
        // P12: stage buf1.A1 (last read prev P56/P7, 2 BARs back);
        //      read af0,bf0,bf1 <- buf0; Q00 then Q01 (bf1's reads overlap Q00)
        STAGE_A(1, 1, S1);
        READ_A4(af0, pA0, 0); READ_B2(bf0, pB0, 0); READ_B2(bf1, pB0, 2);
        PRIO(1); MM16(af0, bf0, 0, 0); MM16(af0, bf1, 0, 2); PRIO(0);
        BAR();
        // P3: stage buf0.B0 (all buf0.B read at P12); read af1; Q11
        STAGE_B(0, 0, S2);
        READ_A4(af1, pA0, 4);
        PRIO(1); MM16(af1, bf1, 4, 2); PRIO(0);
        BAR();
        // P4: stage buf0.B1 + buf0.A0 (A0 rows read P12+P3); Q10; gate buf1
        STAGE_B(0, 1, S2);
        STAGE_A(0, 0, S2);
        PRIO(1); MM16(af1, bf0, 4, 0); PRIO(0);
        VMCNT(6);
        BAR();

        // ---- odd tile 2j+1 (buf1) ----
        // P56: stage buf0.A1 (last read P3, 2 BARs back);
        //      read af0,bf0,bf1 <- buf1; Q00 then Q01
        STAGE_A(0, 1, S2);
        READ_A4(af0, pA1, 0); READ_B2(bf0, pB1, 0); READ_B2(bf1, pB1, 2);
        PRIO(1); MM16(af0, bf0, 0, 0); MM16(af0, bf1, 0, 2); PRIO(0);
        BAR();
        // P7: stage buf1.B0 (all buf1.B read at P56); read af1; Q11
        STAGE_B(1, 0, S3);
        READ_A4(af1, pA1, 4);
        PRIO(1); MM16(af1, bf1, 4, 2); PRIO(0);
        BAR();
        // P8: stage buf1.B1 + buf1.A0 (rows read P56+P7); Q10; gate buf0
        STAGE_B(1, 1, S3);
        STAGE_A(1, 0, S3);
        PRIO(1); MM16(af1, bf0, 4, 0); PRIO(0);
        VMCNT(6);
        BAR();
    }

    // Fused epilogue. C/D layout: n(col) = lane&15, m(row) = quad*4 + reg.
    // X read via its bf16 copy (L2-warm A-panel rows); out stored NT.
    const float one_m_beta = 1.0f - Bp[0];
    const unsigned short* Xh = (const unsigned short*)Xbf;
#pragma unroll
    for (int nt = 0; nt < 4; nt++) {
        const int n = bn0 + wn * 64 + nt * 16 + l16;
        const float br = Br[n];
#pragma unroll
        for (int mt = 0; mt < 8; mt++) {
            const int mbase = bm0 + wm * 128 + mt * 16 + quad * 4;
#pragma unroll
            for (int r = 0; r < 4; r++) {
                const size_t idx = (size_t)(mbase + r) * NDIM + n;
                unsigned int xu = (unsigned int)Xh[idx] << 16;
                float xv;
                __builtin_memcpy(&xv, &xu, 4);
                float v = acc[mt][nt][r] + one_m_beta;
                if (v < 0.0f) v = 0.0f;                 // relu(1 - beta + rowsum)
                float res = 1.0f - br + xv + v;
                if (res < 0.0f) res = 0.0f;             // relu; leaky on relu == id
                __builtin_nontemporal_store(res, &out[idx]);
            }
        }
    }
    (void)X;
}

// Fallback (R6 kernel, proven): in-loop conversion, no workspace needed.
__global__ void resfc_fallback_kernel(
    const float* X, const float* W,
    const float* Bp, const float* Br,
    float* out)
{
    __shared__ __align__(16) unsigned int sA[128 * 16];
    __shared__ __align__(16) unsigned int sB[128 * 16];

    const int t    = threadIdx.x;
    const int lane = t & 63;
    const int wave = t >> 6;
    const int quad = lane >> 4;
    const int l16  = lane & 15;
    const int wm   = wave >> 1;
    const int wn   = wave & 1;

    const int bm0 = blockIdx.y * 128;
    const int bn0 = blockIdx.x * 128;

    const float* gA[4];
    const float* gB[4];
    int ldsIdx[4];
    for (int c = 0; c < 4; c++) {
        const int ch   = t + c * 256;
        const int row  = ch >> 3;
        const int col4 = ch & 7;
        gA[c] = X + (size_t)(bm0 + row) * NDIM + col4 * 4;
        gB[c] = W + (size_t)(bn0 + row) * NDIM + col4 * 4;
        ldsIdx[c] = row * 16 + col4 * 2;
    }

    const bf16x8* pa = (const bf16x8*)sA + (wm * 64 + l16) * 4 + quad;
    const bf16x8* pb = (const bf16x8*)sB + (wn * 64 + l16) * 4 + quad;

    f32x4 acc[4][4];
    for (int i = 0; i < 4; i++)
        for (int j = 0; j < 4; j++)
            for (int r = 0; r < 4; r++)
                acc[i][j][r] = 0.0f;

    for (int k0 = 0; k0 < NDIM; k0 += 32) {
        float4 va[4], vb[4];
        for (int c = 0; c < 4; c++) {
            va[c] = *(const float4*)(gA[c] + k0);
            vb[c] = *(const float4*)(gB[c] + k0);
        }
        __syncthreads();
        for (int c = 0; c < 4; c++) {
            uint2 ua, ub;
            ua.x = pack_bf2(va[c].x, va[c].y);
            ua.y = pack_bf2(va[c].z, va[c].w);
            ub.x = pack_bf2(vb[c].x, vb[c].y);
            ub.y = pack_bf2(vb[c].z, vb[c].w);
            *(uint2*)(sA + ldsIdx[c]) = ua;
            *(uint2*)(sB + ldsIdx[c]) = ub;
        }
        __syncthreads();

        bf16x8 af[4], bfr[4];
        for (int mt = 0; mt < 4; mt++) af[mt]  = pa[mt * 64];
        for (int nt = 0; nt < 4; nt++) bfr[nt] = pb[nt * 64];

        for (int mt = 0; mt < 4; mt++)
            for (int nt = 0; nt < 4; nt++)
                acc[mt][nt] = __builtin_amdgcn_mfma_f32_16x16x32_bf16(
                    af[mt], bfr[nt], acc[mt][nt], 0, 0, 0);
    }

    const float one_m_beta = 1.0f - Bp[0];
    for (int nt = 0; nt < 4; nt++) {
        const int n = bn0 + wn * 64 + nt * 16 + l16;
        const float br = Br[n];
        for (int mt = 0; mt < 4; mt++) {
            const int mbase = bm0 + wm * 64 + mt * 16 + quad * 4;
            for (int r = 0; r < 4; r++) {
                const size_t idx = (size_t)(mbase + r) * NDIM + n;
                float v = acc[mt][nt][r] + one_m_beta;
                if (v < 0.0f) v = 0.0f;
                float res = 1.0f - br + X[idx] + v;
                if (res < 0.0f) res = 0.0f;
                out[idx] = res;
            }
        }
    }
}

extern "C" void kernel_launch(void* const* d_in, const int* in_sizes, int n_in,
                              void* d_out, int out_size, void* d_ws, size_t ws_size,
                              hipStream_t stream) {
    (void)in_sizes; (void)n_in; (void)out_size;

    const float* X  = (const float*)d_in[0];
    const float* W  = (const float*)d_in[1];
    const float* Bp = (const float*)d_in[2];
    const float* Br = (const float*)d_in[3];
    float* out      = (float*)d_out;

    const size_t elems   = (size_t)NDIM * NDIM;          // 16.7M per matrix
    const size_t bf_need = elems * 2 * 2;                // Xbf + Wbf, 2 B each

    if (ws_size >= bf_need) {
        unsigned int* Xbf = (unsigned int*)d_ws;
        unsigned int* Wbf = (unsigned int*)d_ws + elems / 2;   // uint = 2 bf16

        hipLaunchKernelGGL(convert_f32_bf16_kernel, dim3(16384), dim3(256),
                           0, stream, X, Xbf, W, Wbf);
        hipLaunchKernelGGL(ResFCEventuallyLayer_82205674045459_kernel,
                           dim3(256), dim3(512), 0, stream, Xbf, Wbf, X, Bp, Br, out);
    } else {
        hipLaunchKernelGGL(resfc_fallback_kernel,
                           dim3(NDIM / 128, NDIM / 128), dim3(256), 0, stream,
                           X, W, Bp, Br, out);
    }
}